// Round 1
// baseline (455.075 us; speedup 1.0000x reference)
//
#include <hip/hip_runtime.h>
#include <hip/hip_bf16.h>

// Problem constants: x (B,N,D) fp32; per-head SwiGLU FFN H=512.
#define B_ 8192
#define N_ 16
#define D_ 256
#define H_ 512

using bf16x8 = __attribute__((ext_vector_type(8))) short;
using f32x4  = __attribute__((ext_vector_type(4))) float;

__device__ __forceinline__ void gload_lds16(const void* g, void* l) {
    __builtin_amdgcn_global_load_lds(
        (const __attribute__((address_space(1))) void*)g,
        (__attribute__((address_space(3))) void*)l, 16, 0, 0);
}

__device__ __forceinline__ short f2bf(float f) {
    unsigned int u = __float_as_uint(f);
    u += 0x7fffu + ((u >> 16) & 1u);   // round-to-nearest-even
    return (short)(u >> 16);
}

// ---------------------------------------------------------------------------
// k_prep: fp32 weights -> bf16, transposed so K is contiguous for MFMA loads.
//   w1t/w3t layout [n][h][d]  (B^T of (D,H))
//   w2t     layout [n][d][h]  (B^T of (H,D))
// ---------------------------------------------------------------------------
__global__ __launch_bounds__(256) void k_prep(const float* __restrict__ w1,
                                              const float* __restrict__ w3,
                                              const float* __restrict__ w2,
                                              short* __restrict__ w1t,
                                              short* __restrict__ w3t,
                                              short* __restrict__ w2t) {
    int o = blockIdx.x * 256 + threadIdx.x;      // 0 .. N*D*H-1 (2M)
    int n = o >> 17;                              // / (D*H = 131072)
    int r = o & 131071;
    int h = r >> 8, d = r & 255;                  // [n][h][d] out layout
    w1t[o] = f2bf(w1[(size_t)n * 131072 + (size_t)d * 512 + h]);
    w3t[o] = f2bf(w3[(size_t)n * 131072 + (size_t)d * 512 + h]);
    int d2 = r >> 9, h2 = r & 511;                // [n][d][h] out layout
    w2t[o] = f2bf(w2[(size_t)n * 131072 + (size_t)h2 * 256 + d2]);
}

// ---------------------------------------------------------------------------
// k_mix: per-b block. rmsnorm1 -> head_mixing -> +x -> rmsnorm2.
// Writes p (fp32) and pn (bf16), both head-major [head][b][d].
// ---------------------------------------------------------------------------
__global__ __launch_bounds__(256) void k_mix(const float* __restrict__ x,
                                             const float* __restrict__ n1w,
                                             const float* __restrict__ n2w,
                                             float* __restrict__ p_ws,
                                             short* __restrict__ pn_ws) {
    __shared__ float xs[N_ * D_];
    __shared__ float ps[N_ * D_];
    __shared__ float inv1[N_];
    __shared__ float inv2[N_];
    int b = blockIdx.x;
    int t = threadIdx.x;

    const float4* xb4 = (const float4*)(x + (size_t)b * (N_ * D_));
    float4* xs4 = (float4*)xs;
#pragma unroll
    for (int i = 0; i < 4; ++i) xs4[t + i * 256] = xb4[t + i * 256];
    __syncthreads();

    int hh = t >> 4, sub = t & 15;
    float s = 0.f;
#pragma unroll
    for (int j = 0; j < 16; ++j) { float v = xs[hh * 256 + sub * 16 + j]; s += v * v; }
    s += __shfl_xor(s, 1); s += __shfl_xor(s, 2);
    s += __shfl_xor(s, 4); s += __shfl_xor(s, 8);
    if (sub == 0) inv1[hh] = rsqrtf(s * (1.0f / 256.0f) + 1e-6f);
    __syncthreads();

    // p[b, m, n*16+j] = x[b, n, m*16+j]*inv1[n]*n1w[m*16+j] + x[b, m, n*16+j]
    {
        int n = t >> 4, j = t & 15;               // d = t
#pragma unroll 1
        for (int m = 0; m < 16; ++m) {
            float v = xs[n * 256 + m * 16 + j] * inv1[n] * n1w[m * 16 + j]
                    + xs[m * 256 + t];
            ps[m * 256 + t] = v;
        }
    }
    __syncthreads();

    float s2 = 0.f;
#pragma unroll
    for (int j = 0; j < 16; ++j) { float v = ps[hh * 256 + sub * 16 + j]; s2 += v * v; }
    s2 += __shfl_xor(s2, 1); s2 += __shfl_xor(s2, 2);
    s2 += __shfl_xor(s2, 4); s2 += __shfl_xor(s2, 8);
    if (sub == 0) inv2[hh] = rsqrtf(s2 * (1.0f / 256.0f) + 1e-6f);
    __syncthreads();

#pragma unroll 1
    for (int m = 0; m < 16; ++m) {
        float v = ps[m * 256 + t];
        size_t off = ((size_t)m * B_ + b) * D_ + t;
        p_ws[off]  = v;
        pn_ws[off] = f2bf(v * inv2[m] * n2w[t]);
    }
}

// ---------------------------------------------------------------------------
// k_gateup: per head n: G = Pn @ W1, U = Pn @ W3 (M=8192, N=512, K=256),
// fused silu(G)*U epilogue -> hact bf16 [head][b][h].
// m97 structure: 128x128 tile, BK=32, 4 waves x (4x4) 16x16x32 MFMA frags.
// ---------------------------------------------------------------------------
__global__ __launch_bounds__(256) void k_gateup(const short* __restrict__ pn,
                                                const short* __restrict__ w1t,
                                                const short* __restrict__ w3t,
                                                short* __restrict__ hact) {
    int bx = blockIdx.x;
    int nt = bx & 3;             // 512 / 128
    int mt = (bx >> 2) & 63;     // 8192 / 128
    int head = bx >> 8;

    __shared__ short As[128 * 32];
    __shared__ short B1s[128 * 32];
    __shared__ short B3s[128 * 32];

    int t = threadIdx.x;
    int wave = t >> 6, lane = t & 63;
    int rowBase = (wave >> 1) * 64;
    int colBase = (wave & 1) * 64;

    f32x4 accG[4][4], accU[4][4];
#pragma unroll
    for (int m = 0; m < 4; ++m)
#pragma unroll
        for (int nn = 0; nn < 4; ++nn) {
            accG[m][nn] = (f32x4){0.f, 0.f, 0.f, 0.f};
            accU[m][nn] = (f32x4){0.f, 0.f, 0.f, 0.f};
        }

    const short* Ab  = pn  + ((size_t)head * B_ + (size_t)mt * 128) * D_;
    const short* B1b = w1t + ((size_t)head * H_ + (size_t)nt * 128) * D_;
    const short* B3b = w3t + ((size_t)head * H_ + (size_t)nt * 128) * D_;

    int lr = t >> 2;            // 0..63 : tile row of this thread's 16B chunk
    int lk = (t & 3) * 8;       // k-offset in elements

    for (int k0 = 0; k0 < 256; k0 += 32) {
        gload_lds16(Ab  + (size_t)lr * 256 + k0 + lk,        &As[t * 8]);
        gload_lds16(Ab  + (size_t)(lr + 64) * 256 + k0 + lk, &As[2048 + t * 8]);
        gload_lds16(B1b + (size_t)lr * 256 + k0 + lk,        &B1s[t * 8]);
        gload_lds16(B1b + (size_t)(lr + 64) * 256 + k0 + lk, &B1s[2048 + t * 8]);
        gload_lds16(B3b + (size_t)lr * 256 + k0 + lk,        &B3s[t * 8]);
        gload_lds16(B3b + (size_t)(lr + 64) * 256 + k0 + lk, &B3s[2048 + t * 8]);
        __syncthreads();

        int kg = (lane >> 4) * 8;
        int l16 = lane & 15;
        bf16x8 aF[4], b1F[4], b3F[4];
#pragma unroll
        for (int m = 0; m < 4; ++m)
            aF[m] = *(const bf16x8*)&As[(rowBase + m * 16 + l16) * 32 + kg];
#pragma unroll
        for (int nn = 0; nn < 4; ++nn) {
            b1F[nn] = *(const bf16x8*)&B1s[(colBase + nn * 16 + l16) * 32 + kg];
            b3F[nn] = *(const bf16x8*)&B3s[(colBase + nn * 16 + l16) * 32 + kg];
        }
#pragma unroll
        for (int m = 0; m < 4; ++m)
#pragma unroll
            for (int nn = 0; nn < 4; ++nn) {
                accG[m][nn] = __builtin_amdgcn_mfma_f32_16x16x32_bf16(
                    aF[m], b1F[nn], accG[m][nn], 0, 0, 0);
                accU[m][nn] = __builtin_amdgcn_mfma_f32_16x16x32_bf16(
                    aF[m], b3F[nn], accU[m][nn], 0, 0, 0);
            }
        __syncthreads();
    }

    // epilogue: h = silu(g)*u; C/D layout: col = lane&15, row = (lane>>4)*4 + r
    int l16 = lane & 15, lrg = (lane >> 4) * 4;
    size_t hbase = (size_t)head * B_ * H_;
#pragma unroll
    for (int m = 0; m < 4; ++m) {
        int row0 = mt * 128 + rowBase + m * 16 + lrg;
#pragma unroll
        for (int nn = 0; nn < 4; ++nn) {
            int col = nt * 128 + colBase + nn * 16 + l16;
#pragma unroll
            for (int r = 0; r < 4; ++r) {
                float g = accG[m][nn][r];
                float u = accU[m][nn][r];
                float hv = g * (1.0f / (1.0f + __expf(-g))) * u;
                hact[hbase + (size_t)(row0 + r) * H_ + col] = f2bf(hv);
            }
        }
    }
}

// ---------------------------------------------------------------------------
// k_down: per head n: Q = Hact @ W2 (M=8192, N=256, K=512) + p, write (B,N,D).
// ---------------------------------------------------------------------------
__global__ __launch_bounds__(256) void k_down(const short* __restrict__ hact,
                                              const short* __restrict__ w2t,
                                              const float* __restrict__ p_ws,
                                              float* __restrict__ out) {
    int bx = blockIdx.x;
    int nt = bx & 1;             // 256 / 128
    int mt = (bx >> 1) & 63;     // 8192 / 128
    int head = bx >> 7;

    __shared__ short As[128 * 32];
    __shared__ short Bs[128 * 32];

    int t = threadIdx.x;
    int wave = t >> 6, lane = t & 63;
    int rowBase = (wave >> 1) * 64;
    int colBase = (wave & 1) * 64;

    f32x4 acc[4][4];
#pragma unroll
    for (int m = 0; m < 4; ++m)
#pragma unroll
        for (int nn = 0; nn < 4; ++nn) acc[m][nn] = (f32x4){0.f, 0.f, 0.f, 0.f};

    const short* Ab = hact + ((size_t)head * B_ + (size_t)mt * 128) * H_;
    const short* Bb = w2t  + ((size_t)head * D_ + (size_t)nt * 128) * H_;

    int lr = t >> 2;
    int lk = (t & 3) * 8;

    for (int k0 = 0; k0 < 512; k0 += 32) {
        gload_lds16(Ab + (size_t)lr * 512 + k0 + lk,        &As[t * 8]);
        gload_lds16(Ab + (size_t)(lr + 64) * 512 + k0 + lk, &As[2048 + t * 8]);
        gload_lds16(Bb + (size_t)lr * 512 + k0 + lk,        &Bs[t * 8]);
        gload_lds16(Bb + (size_t)(lr + 64) * 512 + k0 + lk, &Bs[2048 + t * 8]);
        __syncthreads();

        int kg = (lane >> 4) * 8;
        int l16 = lane & 15;
        bf16x8 aF[4], bF[4];
#pragma unroll
        for (int m = 0; m < 4; ++m)
            aF[m] = *(const bf16x8*)&As[(rowBase + m * 16 + l16) * 32 + kg];
#pragma unroll
        for (int nn = 0; nn < 4; ++nn)
            bF[nn] = *(const bf16x8*)&Bs[(colBase + nn * 16 + l16) * 32 + kg];
#pragma unroll
        for (int m = 0; m < 4; ++m)
#pragma unroll
            for (int nn = 0; nn < 4; ++nn)
                acc[m][nn] = __builtin_amdgcn_mfma_f32_16x16x32_bf16(
                    aF[m], bF[nn], acc[m][nn], 0, 0, 0);
        __syncthreads();
    }

    int l16 = lane & 15, lrg = (lane >> 4) * 4;
#pragma unroll
    for (int m = 0; m < 4; ++m) {
        int row0 = mt * 128 + rowBase + m * 16 + lrg;
#pragma unroll
        for (int nn = 0; nn < 4; ++nn) {
            int col = nt * 128 + colBase + nn * 16 + l16;
#pragma unroll
            for (int r = 0; r < 4; ++r) {
                int row = row0 + r;
                float pv = p_ws[((size_t)head * B_ + row) * D_ + col];
                out[(size_t)row * (N_ * D_) + head * D_ + col] = acc[m][nn][r] + pv;
            }
        }
    }
}

// ---------------------------------------------------------------------------
extern "C" void kernel_launch(void* const* d_in, const int* in_sizes, int n_in,
                              void* d_out, int out_size, void* d_ws, size_t ws_size,
                              hipStream_t stream) {
    const float* x   = (const float*)d_in[0];
    const float* n1w = (const float*)d_in[1];
    const float* n2w = (const float*)d_in[2];
    const float* w1  = (const float*)d_in[3];
    const float* w3  = (const float*)d_in[4];
    const float* w2  = (const float*)d_in[5];
    float* out = (float*)d_out;

    char* ws = (char*)d_ws;
    // ws layout (total ~332 MiB):
    short* w1t  = (short*)(ws);                       //  4 MiB (N*D*H bf16)
    short* w3t  = (short*)(ws + (4ull  << 20));       //  4 MiB
    short* w2t  = (short*)(ws + (8ull  << 20));       //  4 MiB
    short* pn   = (short*)(ws + (12ull << 20));       // 64 MiB (bf16, head-major)
    float* p    = (float*)(ws + (76ull << 20));       // 128 MiB (fp32, head-major)
    short* hact = (short*)(ws + (204ull << 20));      // 128 MiB (bf16, head-major)

    k_prep<<<(N_ * D_ * H_) / 256, 256, 0, stream>>>(w1, w3, w2, w1t, w3t, w2t);
    k_mix<<<B_, 256, 0, stream>>>(x, n1w, n2w, p, pn);
    k_gateup<<<N_ * (B_ / 128) * (H_ / 128), 256, 0, stream>>>(pn, w1t, w3t, hact);
    k_down<<<N_ * (B_ / 128) * (D_ / 128), 256, 0, stream>>>(hact, w2t, p, out);
}

// Round 2
// 317.698 us; speedup vs baseline: 1.4324x; 1.4324x over previous
//
#include <hip/hip_runtime.h>
#include <hip/hip_bf16.h>

// Problem constants: x (B,N,D) fp32; per-head SwiGLU FFN H=512.
#define B_ 8192
#define N_ 16
#define D_ 256
#define H_ 512

using bf16x8 = __attribute__((ext_vector_type(8))) short;
using f32x4  = __attribute__((ext_vector_type(4))) float;

__device__ __forceinline__ void gload_lds16(const void* g, void* l) {
    __builtin_amdgcn_global_load_lds(
        (const __attribute__((address_space(1))) void*)g,
        (__attribute__((address_space(3))) void*)l, 16, 0, 0);
}

__device__ __forceinline__ short f2bf(float f) {
    unsigned int u = __float_as_uint(f);
    u += 0x7fffu + ((u >> 16) & 1u);   // round-to-nearest-even
    return (short)(u >> 16);
}

// ---------------------------------------------------------------------------
// k_prep: fp32 weights -> bf16, transposed so K is contiguous for MFMA loads.
//   w1t/w3t layout [n][h][d]  (B^T of (D,H))
//   w2t     layout [n][d][h]  (B^T of (H,D))
// ---------------------------------------------------------------------------
__global__ __launch_bounds__(256) void k_prep(const float* __restrict__ w1,
                                              const float* __restrict__ w3,
                                              const float* __restrict__ w2,
                                              short* __restrict__ w1t,
                                              short* __restrict__ w3t,
                                              short* __restrict__ w2t) {
    int o = blockIdx.x * 256 + threadIdx.x;      // 0 .. N*D*H-1 (2M)
    int n = o >> 17;                              // / (D*H = 131072)
    int r = o & 131071;
    int h = r >> 8, d = r & 255;                  // [n][h][d] out layout
    w1t[o] = f2bf(w1[(size_t)n * 131072 + (size_t)d * 512 + h]);
    w3t[o] = f2bf(w3[(size_t)n * 131072 + (size_t)d * 512 + h]);
    int d2 = r >> 9, h2 = r & 511;                // [n][d][h] out layout
    w2t[o] = f2bf(w2[(size_t)n * 131072 + (size_t)h2 * 256 + d2]);
}

// ---------------------------------------------------------------------------
// k_mix: per-b block. rmsnorm1 -> head_mixing -> +x -> rmsnorm2.
// Writes p (fp32) and pn (bf16), both head-major [head][b][d].
// ---------------------------------------------------------------------------
__global__ __launch_bounds__(256) void k_mix(const float* __restrict__ x,
                                             const float* __restrict__ n1w,
                                             const float* __restrict__ n2w,
                                             float* __restrict__ p_ws,
                                             short* __restrict__ pn_ws) {
    __shared__ float xs[N_ * D_];
    __shared__ float ps[N_ * D_];
    __shared__ float inv1[N_];
    __shared__ float inv2[N_];
    int b = blockIdx.x;
    int t = threadIdx.x;

    const float4* xb4 = (const float4*)(x + (size_t)b * (N_ * D_));
    float4* xs4 = (float4*)xs;
#pragma unroll
    for (int i = 0; i < 4; ++i) xs4[t + i * 256] = xb4[t + i * 256];
    __syncthreads();

    int hh = t >> 4, sub = t & 15;
    float s = 0.f;
#pragma unroll
    for (int j = 0; j < 16; ++j) { float v = xs[hh * 256 + sub * 16 + j]; s += v * v; }
    s += __shfl_xor(s, 1); s += __shfl_xor(s, 2);
    s += __shfl_xor(s, 4); s += __shfl_xor(s, 8);
    if (sub == 0) inv1[hh] = rsqrtf(s * (1.0f / 256.0f) + 1e-6f);
    __syncthreads();

    // p[b, m, n*16+j] = x[b, n, m*16+j]*inv1[n]*n1w[m*16+j] + x[b, m, n*16+j]
    {
        int n = t >> 4, j = t & 15;               // d = t
#pragma unroll 1
        for (int m = 0; m < 16; ++m) {
            float v = xs[n * 256 + m * 16 + j] * inv1[n] * n1w[m * 16 + j]
                    + xs[m * 256 + t];
            ps[m * 256 + t] = v;
        }
    }
    __syncthreads();

    float s2 = 0.f;
#pragma unroll
    for (int j = 0; j < 16; ++j) { float v = ps[hh * 256 + sub * 16 + j]; s2 += v * v; }
    s2 += __shfl_xor(s2, 1); s2 += __shfl_xor(s2, 2);
    s2 += __shfl_xor(s2, 4); s2 += __shfl_xor(s2, 8);
    if (sub == 0) inv2[hh] = rsqrtf(s2 * (1.0f / 256.0f) + 1e-6f);
    __syncthreads();

#pragma unroll 1
    for (int m = 0; m < 16; ++m) {
        float v = ps[m * 256 + t];
        size_t off = ((size_t)m * B_ + b) * D_ + t;
        p_ws[off]  = v;
        pn_ws[off] = f2bf(v * inv2[m] * n2w[t]);
    }
}

// ---------------------------------------------------------------------------
// k_gateup v2: per head n: G = Pn @ W1, U = Pn @ W3 (M=8192, Nh=512, K=256),
// fused silu(G)*U -> hact bf16 [head][b][h].
// Tile 128(M) x 64(H), BK=32, 4 waves in 2x2, per-wave 64x32.
// acc = accG[4][2] + accU[4][2] = 64 regs -> 2 waves/SIMD occupancy.
// ---------------------------------------------------------------------------
__global__ __launch_bounds__(256, 2) void k_gateup(const short* __restrict__ pn,
                                                   const short* __restrict__ w1t,
                                                   const short* __restrict__ w3t,
                                                   short* __restrict__ hact) {
    // XCD-aware bijective swizzle: 8192 blocks, 1024 per XCD chunk.
    int bid = blockIdx.x;
    int bx = (bid & 7) * 1024 + (bid >> 3);
    int nt = bx & 7;             // H / 64
    int mt = (bx >> 3) & 63;     // 8192 / 128
    int head = bx >> 9;

    __shared__ short As[128 * 32];   // 8 KiB
    __shared__ short B1s[64 * 32];   // 4 KiB
    __shared__ short B3s[64 * 32];   // 4 KiB

    int t = threadIdx.x;
    int wave = t >> 6, lane = t & 63;
    int rowBase = (wave >> 1) * 64;
    int colBase = (wave & 1) * 32;

    f32x4 accG[4][2], accU[4][2];
#pragma unroll
    for (int m = 0; m < 4; ++m)
#pragma unroll
        for (int nn = 0; nn < 2; ++nn) {
            accG[m][nn] = (f32x4){0.f, 0.f, 0.f, 0.f};
            accU[m][nn] = (f32x4){0.f, 0.f, 0.f, 0.f};
        }

    const short* Ab  = pn  + ((size_t)head * B_ + (size_t)mt * 128) * D_;
    const short* B1b = w1t + ((size_t)head * H_ + (size_t)nt * 64) * D_;
    const short* B3b = w3t + ((size_t)head * H_ + (size_t)nt * 64) * D_;

    int lr = t >> 2;            // 0..63 : tile row of this thread's 16B chunk
    int lk = (t & 3) * 8;       // k-offset in elements

    for (int k0 = 0; k0 < 256; k0 += 32) {
        gload_lds16(Ab  + (size_t)lr * 256 + k0 + lk,        &As[t * 8]);
        gload_lds16(Ab  + (size_t)(lr + 64) * 256 + k0 + lk, &As[2048 + t * 8]);
        gload_lds16(B1b + (size_t)lr * 256 + k0 + lk,        &B1s[t * 8]);
        gload_lds16(B3b + (size_t)lr * 256 + k0 + lk,        &B3s[t * 8]);
        __syncthreads();

        int kg = (lane >> 4) * 8;
        int l16 = lane & 15;
        bf16x8 aF[4], b1F[2], b3F[2];
#pragma unroll
        for (int m = 0; m < 4; ++m)
            aF[m] = *(const bf16x8*)&As[(rowBase + m * 16 + l16) * 32 + kg];
#pragma unroll
        for (int nn = 0; nn < 2; ++nn) {
            b1F[nn] = *(const bf16x8*)&B1s[(colBase + nn * 16 + l16) * 32 + kg];
            b3F[nn] = *(const bf16x8*)&B3s[(colBase + nn * 16 + l16) * 32 + kg];
        }
#pragma unroll
        for (int m = 0; m < 4; ++m)
#pragma unroll
            for (int nn = 0; nn < 2; ++nn) {
                accG[m][nn] = __builtin_amdgcn_mfma_f32_16x16x32_bf16(
                    aF[m], b1F[nn], accG[m][nn], 0, 0, 0);
                accU[m][nn] = __builtin_amdgcn_mfma_f32_16x16x32_bf16(
                    aF[m], b3F[nn], accU[m][nn], 0, 0, 0);
            }
        __syncthreads();
    }

    // epilogue: h = silu(g)*u; C/D layout: col = lane&15, row = (lane>>4)*4 + r
    int l16 = lane & 15, lrg = (lane >> 4) * 4;
    size_t hbase = (size_t)head * B_ * H_;
#pragma unroll
    for (int m = 0; m < 4; ++m) {
        int row0 = mt * 128 + rowBase + m * 16 + lrg;
#pragma unroll
        for (int nn = 0; nn < 2; ++nn) {
            int col = nt * 64 + colBase + nn * 16 + l16;
#pragma unroll
            for (int r = 0; r < 4; ++r) {
                float g = accG[m][nn][r];
                float u = accU[m][nn][r];
                float hv = g * (1.0f / (1.0f + __expf(-g))) * u;
                hact[hbase + (size_t)(row0 + r) * H_ + col] = f2bf(hv);
            }
        }
    }
}

// ---------------------------------------------------------------------------
// k_down: per head n: Q = Hact @ W2 (M=8192, N=256, K=512) + p, write (B,N,D).
// ---------------------------------------------------------------------------
__global__ __launch_bounds__(256, 2) void k_down(const short* __restrict__ hact,
                                                 const short* __restrict__ w2t,
                                                 const float* __restrict__ p_ws,
                                                 float* __restrict__ out) {
    // XCD-aware bijective swizzle: 2048 blocks, 256 per XCD chunk.
    int bid = blockIdx.x;
    int bx = (bid & 7) * 256 + (bid >> 3);
    int nt = bx & 1;             // 256 / 128
    int mt = (bx >> 1) & 63;     // 8192 / 128
    int head = bx >> 7;

    __shared__ short As[128 * 32];
    __shared__ short Bs[128 * 32];

    int t = threadIdx.x;
    int wave = t >> 6, lane = t & 63;
    int rowBase = (wave >> 1) * 64;
    int colBase = (wave & 1) * 64;

    f32x4 acc[4][4];
#pragma unroll
    for (int m = 0; m < 4; ++m)
#pragma unroll
        for (int nn = 0; nn < 4; ++nn) acc[m][nn] = (f32x4){0.f, 0.f, 0.f, 0.f};

    const short* Ab = hact + ((size_t)head * B_ + (size_t)mt * 128) * H_;
    const short* Bb = w2t  + ((size_t)head * D_ + (size_t)nt * 128) * H_;

    int lr = t >> 2;
    int lk = (t & 3) * 8;

    for (int k0 = 0; k0 < 512; k0 += 32) {
        gload_lds16(Ab + (size_t)lr * 512 + k0 + lk,        &As[t * 8]);
        gload_lds16(Ab + (size_t)(lr + 64) * 512 + k0 + lk, &As[2048 + t * 8]);
        gload_lds16(Bb + (size_t)lr * 512 + k0 + lk,        &Bs[t * 8]);
        gload_lds16(Bb + (size_t)(lr + 64) * 512 + k0 + lk, &Bs[2048 + t * 8]);
        __syncthreads();

        int kg = (lane >> 4) * 8;
        int l16 = lane & 15;
        bf16x8 aF[4], bF[4];
#pragma unroll
        for (int m = 0; m < 4; ++m)
            aF[m] = *(const bf16x8*)&As[(rowBase + m * 16 + l16) * 32 + kg];
#pragma unroll
        for (int nn = 0; nn < 4; ++nn)
            bF[nn] = *(const bf16x8*)&Bs[(colBase + nn * 16 + l16) * 32 + kg];
#pragma unroll
        for (int m = 0; m < 4; ++m)
#pragma unroll
            for (int nn = 0; nn < 4; ++nn)
                acc[m][nn] = __builtin_amdgcn_mfma_f32_16x16x32_bf16(
                    aF[m], bF[nn], acc[m][nn], 0, 0, 0);
        __syncthreads();
    }

    int l16 = lane & 15, lrg = (lane >> 4) * 4;
#pragma unroll
    for (int m = 0; m < 4; ++m) {
        int row0 = mt * 128 + rowBase + m * 16 + lrg;
#pragma unroll
        for (int nn = 0; nn < 4; ++nn) {
            int col = nt * 128 + colBase + nn * 16 + l16;
#pragma unroll
            for (int r = 0; r < 4; ++r) {
                int row = row0 + r;
                float pv = p_ws[((size_t)head * B_ + row) * D_ + col];
                out[(size_t)row * (N_ * D_) + head * D_ + col] = acc[m][nn][r] + pv;
            }
        }
    }
}

// ---------------------------------------------------------------------------
extern "C" void kernel_launch(void* const* d_in, const int* in_sizes, int n_in,
                              void* d_out, int out_size, void* d_ws, size_t ws_size,
                              hipStream_t stream) {
    const float* x   = (const float*)d_in[0];
    const float* n1w = (const float*)d_in[1];
    const float* n2w = (const float*)d_in[2];
    const float* w1  = (const float*)d_in[3];
    const float* w3  = (const float*)d_in[4];
    const float* w2  = (const float*)d_in[5];
    float* out = (float*)d_out;

    char* ws = (char*)d_ws;
    // ws layout (total ~332 MiB):
    short* w1t  = (short*)(ws);                       //  4 MiB (N*D*H bf16)
    short* w3t  = (short*)(ws + (4ull  << 20));       //  4 MiB
    short* w2t  = (short*)(ws + (8ull  << 20));       //  4 MiB
    short* pn   = (short*)(ws + (12ull << 20));       // 64 MiB (bf16, head-major)
    float* p    = (float*)(ws + (76ull << 20));       // 128 MiB (fp32, head-major)
    short* hact = (short*)(ws + (204ull << 20));      // 128 MiB (bf16, head-major)

    k_prep<<<(N_ * D_ * H_) / 256, 256, 0, stream>>>(w1, w3, w2, w1t, w3t, w2t);
    k_mix<<<B_, 256, 0, stream>>>(x, n1w, n2w, p, pn);
    k_gateup<<<N_ * (B_ / 128) * (H_ / 64), 256, 0, stream>>>(pn, w1t, w3t, hact);
    k_down<<<N_ * (B_ / 128) * (D_ / 128), 256, 0, stream>>>(hact, w2t, p, out);
}

// Round 4
// 312.944 us; speedup vs baseline: 1.4542x; 1.0152x over previous
//
#include <hip/hip_runtime.h>
#include <hip/hip_bf16.h>

// Problem constants: x (B,N,D) fp32; per-head SwiGLU FFN H=512.
#define B_ 8192
#define N_ 16
#define D_ 256
#define H_ 512

using bf16x8 = __attribute__((ext_vector_type(8))) short;
using f32x4  = __attribute__((ext_vector_type(4))) float;

__device__ __forceinline__ void gload_lds16(const void* g, void* l) {
    __builtin_amdgcn_global_load_lds(
        (const __attribute__((address_space(1))) void*)g,
        (__attribute__((address_space(3))) void*)l, 16, 0, 0);
}

__device__ __forceinline__ short f2bf(float f) {
    unsigned int u = __float_as_uint(f);
    u += 0x7fffu + ((u >> 16) & 1u);   // round-to-nearest-even
    return (short)(u >> 16);
}

__device__ __forceinline__ float bf2f(short s) {
    return __uint_as_float(((unsigned int)(unsigned short)s) << 16);
}

// ---------------------------------------------------------------------------
// Swizzled staging (rule 21: linear LDS dest + inverse-swizzled global src).
// Panel of ROWS x 64 bf16 (128 B LDS rows). Element [row][kg*8+j] lives at
// lds[row*64 + ((kg ^ (row&7))<<3) + j]. 256 threads, 32 rows per round.
// ---------------------------------------------------------------------------
template<int ROWS>
__device__ __forceinline__ void stage_sw(const short* __restrict__ g, int gs,
                                         short* lds, int t) {
#pragma unroll
    for (int rnd = 0; rnd < ROWS / 32; ++rnd) {
        int dr = rnd * 32 + (t >> 3);
        int c = (t & 7) ^ (dr & 7);
        gload_lds16(g + (size_t)dr * gs + c * 8, &lds[rnd * 2048 + t * 8]);
    }
}

// Swizzled fragment read: row-major [*,64] bf16, XOR slot swizzle.
__device__ __forceinline__ bf16x8 fragsw(const short* buf, int row, int kg) {
    return *(const bf16x8*)&buf[(row << 6) + (((kg ^ row) & 7) << 3)];
}

// ---------------------------------------------------------------------------
// k_prep: fp32 weights -> bf16, transposed so K is contiguous for MFMA loads.
//   w1t/w3t layout [n][h][d]  (B^T of (D,H))
//   w2t     layout [n][d][h]  (B^T of (H,D))
// ---------------------------------------------------------------------------
__global__ __launch_bounds__(256) void k_prep(const float* __restrict__ w1,
                                              const float* __restrict__ w3,
                                              const float* __restrict__ w2,
                                              short* __restrict__ w1t,
                                              short* __restrict__ w3t,
                                              short* __restrict__ w2t) {
    int o = blockIdx.x * 256 + threadIdx.x;      // 0 .. N*D*H-1 (2M)
    int n = o >> 17;                              // / (D*H = 131072)
    int r = o & 131071;
    int h = r >> 8, d = r & 255;                  // [n][h][d] out layout
    w1t[o] = f2bf(w1[(size_t)n * 131072 + (size_t)d * 512 + h]);
    w3t[o] = f2bf(w3[(size_t)n * 131072 + (size_t)d * 512 + h]);
    int d2 = r >> 9, h2 = r & 511;                // [n][d][h] out layout
    w2t[o] = f2bf(w2[(size_t)n * 131072 + (size_t)h2 * 256 + d2]);
}

// ---------------------------------------------------------------------------
// k_mix: per-b block. rmsnorm1 -> head_mixing -> +x -> rmsnorm2.
// Writes pb (bf16) and pn (bf16), both head-major [head][b][d].
// ---------------------------------------------------------------------------
__global__ __launch_bounds__(256) void k_mix(const float* __restrict__ x,
                                             const float* __restrict__ n1w,
                                             const float* __restrict__ n2w,
                                             short* __restrict__ pb_ws,
                                             short* __restrict__ pn_ws) {
    __shared__ float xs[N_ * D_];
    __shared__ float ps[N_ * D_];
    __shared__ float inv1[N_];
    __shared__ float inv2[N_];
    int b = blockIdx.x;
    int t = threadIdx.x;

    const float4* xb4 = (const float4*)(x + (size_t)b * (N_ * D_));
    float4* xs4 = (float4*)xs;
#pragma unroll
    for (int i = 0; i < 4; ++i) xs4[t + i * 256] = xb4[t + i * 256];
    __syncthreads();

    int hh = t >> 4, sub = t & 15;
    float s = 0.f;
#pragma unroll
    for (int j = 0; j < 16; ++j) { float v = xs[hh * 256 + sub * 16 + j]; s += v * v; }
    s += __shfl_xor(s, 1); s += __shfl_xor(s, 2);
    s += __shfl_xor(s, 4); s += __shfl_xor(s, 8);
    if (sub == 0) inv1[hh] = rsqrtf(s * (1.0f / 256.0f) + 1e-6f);
    __syncthreads();

    // p[b, m, n*16+j] = x[b, n, m*16+j]*inv1[n]*n1w[m*16+j] + x[b, m, n*16+j]
    {
        int n = t >> 4, j = t & 15;               // d = t
#pragma unroll 1
        for (int m = 0; m < 16; ++m) {
            float v = xs[n * 256 + m * 16 + j] * inv1[n] * n1w[m * 16 + j]
                    + xs[m * 256 + t];
            ps[m * 256 + t] = v;
        }
    }
    __syncthreads();

    float s2 = 0.f;
#pragma unroll
    for (int j = 0; j < 16; ++j) { float v = ps[hh * 256 + sub * 16 + j]; s2 += v * v; }
    s2 += __shfl_xor(s2, 1); s2 += __shfl_xor(s2, 2);
    s2 += __shfl_xor(s2, 4); s2 += __shfl_xor(s2, 8);
    if (sub == 0) inv2[hh] = rsqrtf(s2 * (1.0f / 256.0f) + 1e-6f);
    __syncthreads();

#pragma unroll 1
    for (int m = 0; m < 16; ++m) {
        float v = ps[m * 256 + t];
        size_t off = ((size_t)m * B_ + b) * D_ + t;
        pb_ws[off] = f2bf(v);
        pn_ws[off] = f2bf(v * inv2[m] * n2w[t]);
    }
}

// ---------------------------------------------------------------------------
// k_gateup v3: per head n: G = Pn @ W1, U = Pn @ W3 (M=8192, Nh=512, K=256),
// fused silu(G)*U -> hact bf16 [head][b][h].
// Tile 128(M) x 64(H), BK=64, double-buffered LDS with 2-phase prefetch,
// XOR-swizzled staging/reads (conflict-free ds_read_b128).
// ---------------------------------------------------------------------------
__global__ __launch_bounds__(256, 2) void k_gateup(const short* __restrict__ pn,
                                                   const short* __restrict__ w1t,
                                                   const short* __restrict__ w3t,
                                                   short* __restrict__ hact) {
    // XCD-aware bijective swizzle: 8192 blocks, 1024 per XCD chunk.
    int bid = blockIdx.x;
    int bx = (bid & 7) * 1024 + (bid >> 3);
    int nt = bx & 7;             // H / 64
    int mt = (bx >> 3) & 63;     // 8192 / 128
    int head = bx >> 9;

    __shared__ short As[2][128 * 64];   // 2 x 16 KiB
    __shared__ short B1s[2][64 * 64];   // 2 x 8 KiB
    __shared__ short B3s[2][64 * 64];   // 2 x 8 KiB

    int t = threadIdx.x;
    int wave = t >> 6, lane = t & 63;
    int rowBase = (wave >> 1) * 64;
    int colBase = (wave & 1) * 32;
    int l16 = lane & 15, kq = lane >> 4;

    f32x4 accG[4][2], accU[4][2];
#pragma unroll
    for (int m = 0; m < 4; ++m)
#pragma unroll
        for (int nn = 0; nn < 2; ++nn) {
            accG[m][nn] = (f32x4){0.f, 0.f, 0.f, 0.f};
            accU[m][nn] = (f32x4){0.f, 0.f, 0.f, 0.f};
        }

    const short* Ab  = pn  + ((size_t)head * B_ + (size_t)mt * 128) * D_;
    const short* B1b = w1t + ((size_t)head * H_ + (size_t)nt * 64) * D_;
    const short* B3b = w3t + ((size_t)head * H_ + (size_t)nt * 64) * D_;

    // prologue: stage k-tile 0
    stage_sw<128>(Ab,  D_, &As[0][0],  t);
    stage_sw<64> (B1b, D_, &B1s[0][0], t);
    stage_sw<64> (B3b, D_, &B3s[0][0], t);
    __syncthreads();

    int cur = 0;
#pragma unroll
    for (int kt = 0; kt < 4; ++kt) {
        if (kt < 3) {   // issue next-tile loads BEFORE compute (overlap)
            int k0 = (kt + 1) * 64;
            stage_sw<128>(Ab  + k0, D_, &As[cur ^ 1][0],  t);
            stage_sw<64> (B1b + k0, D_, &B1s[cur ^ 1][0], t);
            stage_sw<64> (B3b + k0, D_, &B3s[cur ^ 1][0], t);
        }
        const short* Ap  = &As[cur][0];
        const short* B1p = &B1s[cur][0];
        const short* B3p = &B3s[cur][0];
#pragma unroll
        for (int ks = 0; ks < 2; ++ks) {
            int kg = ks * 4 + kq;
            bf16x8 aF[4], b1F[2], b3F[2];
#pragma unroll
            for (int m = 0; m < 4; ++m)
                aF[m] = fragsw(Ap, rowBase + m * 16 + l16, kg);
#pragma unroll
            for (int nn = 0; nn < 2; ++nn) {
                b1F[nn] = fragsw(B1p, colBase + nn * 16 + l16, kg);
                b3F[nn] = fragsw(B3p, colBase + nn * 16 + l16, kg);
            }
#pragma unroll
            for (int m = 0; m < 4; ++m)
#pragma unroll
                for (int nn = 0; nn < 2; ++nn) {
                    accG[m][nn] = __builtin_amdgcn_mfma_f32_16x16x32_bf16(
                        aF[m], b1F[nn], accG[m][nn], 0, 0, 0);
                    accU[m][nn] = __builtin_amdgcn_mfma_f32_16x16x32_bf16(
                        aF[m], b3F[nn], accU[m][nn], 0, 0, 0);
                }
        }
        if (kt < 3) __syncthreads();
        cur ^= 1;
    }

    // epilogue: h = silu(g)*u; C/D layout: col = lane&15, row = (lane>>4)*4 + r
    int lrg = (lane >> 4) * 4;
    size_t hbase = (size_t)head * B_ * H_;
#pragma unroll
    for (int m = 0; m < 4; ++m) {
        int row0 = mt * 128 + rowBase + m * 16 + lrg;
#pragma unroll
        for (int nn = 0; nn < 2; ++nn) {
            int col = nt * 64 + colBase + nn * 16 + l16;
#pragma unroll
            for (int r = 0; r < 4; ++r) {
                float g = accG[m][nn][r];
                float u = accU[m][nn][r];
                float hv = g * (1.0f / (1.0f + __expf(-g))) * u;
                hact[hbase + (size_t)(row0 + r) * H_ + col] = f2bf(hv);
            }
        }
    }
}

// ---------------------------------------------------------------------------
// k_down v3: per head n: Q = Hact @ W2 (M=8192, N=256, K=512) + p, -> (B,N,D).
// Tile 128x128, BK=64, double-buffered prefetch, swizzled LDS.
// ---------------------------------------------------------------------------
__global__ __launch_bounds__(256, 2) void k_down(const short* __restrict__ hact,
                                                 const short* __restrict__ w2t,
                                                 const short* __restrict__ pb,
                                                 float* __restrict__ out) {
    // XCD-aware bijective swizzle: 2048 blocks, 256 per XCD chunk.
    int bid = blockIdx.x;
    int bx = (bid & 7) * 256 + (bid >> 3);
    int nt = bx & 1;             // 256 / 128
    int mt = (bx >> 1) & 63;     // 8192 / 128
    int head = bx >> 7;

    __shared__ short As[2][128 * 64];   // 2 x 16 KiB
    __shared__ short Bs[2][128 * 64];   // 2 x 16 KiB

    int t = threadIdx.x;
    int wave = t >> 6, lane = t & 63;
    int rowBase = (wave >> 1) * 64;
    int colBase = (wave & 1) * 64;
    int l16 = lane & 15, kq = lane >> 4;

    f32x4 acc[4][4];
#pragma unroll
    for (int m = 0; m < 4; ++m)
#pragma unroll
        for (int nn = 0; nn < 4; ++nn) acc[m][nn] = (f32x4){0.f, 0.f, 0.f, 0.f};

    const short* Ab = hact + ((size_t)head * B_ + (size_t)mt * 128) * H_;
    const short* Bb = w2t  + ((size_t)head * D_ + (size_t)nt * 128) * H_;

    stage_sw<128>(Ab, H_, &As[0][0], t);
    stage_sw<128>(Bb, H_, &Bs[0][0], t);
    __syncthreads();

    int cur = 0;
#pragma unroll
    for (int kt = 0; kt < 8; ++kt) {
        if (kt < 7) {
            int k0 = (kt + 1) * 64;
            stage_sw<128>(Ab + k0, H_, &As[cur ^ 1][0], t);
            stage_sw<128>(Bb + k0, H_, &Bs[cur ^ 1][0], t);
        }
        const short* Ap = &As[cur][0];
        const short* Bp = &Bs[cur][0];
#pragma unroll
        for (int ks = 0; ks < 2; ++ks) {
            int kg = ks * 4 + kq;
            bf16x8 aF[4], bF[4];
#pragma unroll
            for (int m = 0; m < 4; ++m)
                aF[m] = fragsw(Ap, rowBase + m * 16 + l16, kg);
#pragma unroll
            for (int nn = 0; nn < 4; ++nn)
                bF[nn] = fragsw(Bp, colBase + nn * 16 + l16, kg);
#pragma unroll
            for (int m = 0; m < 4; ++m)
#pragma unroll
                for (int nn = 0; nn < 4; ++nn)
                    acc[m][nn] = __builtin_amdgcn_mfma_f32_16x16x32_bf16(
                        aF[m], bF[nn], acc[m][nn], 0, 0, 0);
        }
        if (kt < 7) __syncthreads();
        cur ^= 1;
    }

    int lrg = (lane >> 4) * 4;
#pragma unroll
    for (int m = 0; m < 4; ++m) {
        int row0 = mt * 128 + rowBase + m * 16 + lrg;
#pragma unroll
        for (int nn = 0; nn < 4; ++nn) {
            int col = nt * 128 + colBase + nn * 16 + l16;
#pragma unroll
            for (int r = 0; r < 4; ++r) {
                int row = row0 + r;
                float pv = bf2f(pb[((size_t)head * B_ + row) * D_ + col]);
                out[(size_t)row * (N_ * D_) + head * D_ + col] = acc[m][nn][r] + pv;
            }
        }
    }
}

// ---------------------------------------------------------------------------
extern "C" void kernel_launch(void* const* d_in, const int* in_sizes, int n_in,
                              void* d_out, int out_size, void* d_ws, size_t ws_size,
                              hipStream_t stream) {
    const float* x   = (const float*)d_in[0];
    const float* n1w = (const float*)d_in[1];
    const float* n2w = (const float*)d_in[2];
    const float* w1  = (const float*)d_in[3];
    const float* w3  = (const float*)d_in[4];
    const float* w2  = (const float*)d_in[5];
    float* out = (float*)d_out;

    char* ws = (char*)d_ws;
    // ws layout (total ~268 MiB):
    short* w1t  = (short*)(ws);                       //  4 MiB (N*D*H bf16)
    short* w3t  = (short*)(ws + (4ull  << 20));       //  4 MiB
    short* w2t  = (short*)(ws + (8ull  << 20));       //  4 MiB
    short* pn   = (short*)(ws + (12ull << 20));       // 64 MiB (bf16, head-major)
    short* pb   = (short*)(ws + (76ull << 20));       // 64 MiB (bf16, head-major)
    short* hact = (short*)(ws + (140ull << 20));      // 128 MiB (bf16, head-major)

    k_prep<<<(N_ * D_ * H_) / 256, 256, 0, stream>>>(w1, w3, w2, w1t, w3t, w2t);
    k_mix<<<B_, 256, 0, stream>>>(x, n1w, n2w, pb, pn);
    k_gateup<<<N_ * (B_ / 128) * (H_ / 64), 256, 0, stream>>>(pn, w1t, w3t, hact);
    k_down<<<N_ * (B_ / 128) * (D_ / 128), 256, 0, stream>>>(hact, w2t, pb, out);
}